// Round 7
// baseline (65654.779 us; speedup 1.0000x reference)
//
#include <hip/hip_runtime.h>

typedef unsigned int u32;

// ---- workspace layout (element offsets are in floats where noted) ----
// hbuf   : f32 [2][32][1024]  ping-pong hidden state (256 KB)
// cstate : f32 [32][1024]     cell state             (128 KB)
// states : f32 [16384][1024]  all h_t, row = t*32+b  (64 MB)
#define OFF_H      0ull
#define OFF_C      262144ull
#define OFF_STATES 1048576ull

static __device__ inline float sigmoidf_(float x) { return 1.f / (1.f + __expf(-x)); }
static __device__ inline float tanhf_(float x) { return 1.f - 2.f / (1.f + __expf(2.f * x)); }

// ---------------------------------------------------------------------------
// init: zero hbuf (65536 f32) and cstate (32768 f32). grid 256 x 256.
// ---------------------------------------------------------------------------
__global__ __launch_bounds__(256) void k_init(float* hb, float* cs) {
    int i = blockIdx.x * 256 + threadIdx.x;
    hb[i] = 0.f;
    if (i < 32768) cs[i] = 0.f;
}

// diagnostic prefill of d_out with 1.0f (16,777,216 floats)
__global__ __launch_bounds__(256) void k_prefill(float* outw) {
    size_t i = (size_t)blockIdx.x * 256u + threadIdx.x;
    size_t stride = (size_t)gridDim.x * 256u;
    for (; i < 16777216ull; i += stride) outw[i] = 1.0f;
}

// ---------------------------------------------------------------------------
// one LSTM time step (launched 512 times, stream-ordered):
//   z = x_t @ [Wi|Wf|Wg|Wc] + h_t @ [Ui|Uf|Ug|Uc] + b
//   i,f,g = sigmoid(zi,zf,zg); c~ = tanh(zc); c = f*c + i*c~; h = g*tanh(c)
// 256 blocks x 256 threads; block owns 4 h-columns (col0 = bid*4).
// Thread role: ks = K-half (0/1), b = batch (0..31), g = gate (0..3);
// accumulates its K-half of z for the block's 4 columns of its gate,
// streaming W/U column-slices from global (64 KB x2 per block, L2-resident
// across the 512 launches). 4.2 KB LDS exchange; c-state in ws (f32).
// No atomics, no fences, no cross-block communication.
// ---------------------------------------------------------------------------
__global__ __launch_bounds__(256) void k_step(
    const float* __restrict__ x,
    const float* __restrict__ Wi, const float* __restrict__ Wf,
    const float* __restrict__ Wg, const float* __restrict__ Wc,
    const float* __restrict__ Ui, const float* __restrict__ Uf,
    const float* __restrict__ Ug, const float* __restrict__ Uc,
    const float* __restrict__ bi, const float* __restrict__ bfv,
    const float* __restrict__ bg, const float* __restrict__ bc,
    float* hbuf, float* cstate, float* states, int t)
{
    __shared__ float zred[2 * 16 * 33];   // [ks][zc(16)][b(32)+pad]
    int tid = threadIdx.x;
    int bid = blockIdx.x;                 // 0..255
    int col0 = bid * 4;
    int ks = tid >> 7;                    // 0..1
    int b  = (tid >> 2) & 31;             // 0..31
    int g  = tid & 3;                     // 0..3

    const float* Bw; const float* Bu;
    if (g == 0)      { Bw = Wi; Bu = Ui; }
    else if (g == 1) { Bw = Wf; Bu = Uf; }
    else if (g == 2) { Bw = Wg; Bu = Ug; }
    else             { Bw = Wc; Bu = Uc; }

    float acc0 = 0.f, acc1 = 0.f, acc2 = 0.f, acc3 = 0.f;

    for (int ph = 0; ph < 2; ph++) {
        const float* arow;
        const float* bbase;
        if (ph == 0) {
            arow  = x + (size_t)b * 524288 + (size_t)t * 1024;   // x[b][t][:]
            bbase = Bw + col0;
        } else {
            arow  = hbuf + (size_t)(t & 1) * 32768 + (size_t)b * 1024;
            bbase = Bu + col0;
        }
        arow  += ks * 512;
        bbase += (size_t)ks * 512 * 1024;
        for (int kb = 0; kb < 64; kb++) {
            float4 a0 = *(const float4*)(arow + kb * 8);
            float4 a1 = *(const float4*)(arow + kb * 8 + 4);
            float aa[8];
            aa[0] = a0.x; aa[1] = a0.y; aa[2] = a0.z; aa[3] = a0.w;
            aa[4] = a1.x; aa[5] = a1.y; aa[6] = a1.z; aa[7] = a1.w;
#pragma unroll
            for (int j = 0; j < 8; j++) {
                float4 bv = *(const float4*)(bbase + (size_t)(kb * 8 + j) * 1024);
                acc0 = __builtin_fmaf(aa[j], bv.x, acc0);
                acc1 = __builtin_fmaf(aa[j], bv.y, acc1);
                acc2 = __builtin_fmaf(aa[j], bv.z, acc2);
                acc3 = __builtin_fmaf(aa[j], bv.w, acc3);
            }
        }
    }
    // publish partials: zred[ks][g*4+c][b]
    zred[ks * 528 + (g * 4 + 0) * 33 + b] = acc0;
    zred[ks * 528 + (g * 4 + 1) * 33 + b] = acc1;
    zred[ks * 528 + (g * 4 + 2) * 33 + b] = acc2;
    zred[ks * 528 + (g * 4 + 3) * 33 + b] = acc3;
    __syncthreads();

    if (tid < 128) {
        int eb = tid >> 2, ecl = tid & 3;
        int col = col0 + ecl;
        float zi = zred[(0 * 4 + ecl) * 33 + eb] + zred[528 + (0 * 4 + ecl) * 33 + eb] + bi[col];
        float zf = zred[(1 * 4 + ecl) * 33 + eb] + zred[528 + (1 * 4 + ecl) * 33 + eb] + bfv[col];
        float zg = zred[(2 * 4 + ecl) * 33 + eb] + zred[528 + (2 * 4 + ecl) * 33 + eb] + bg[col];
        float zc = zred[(3 * 4 + ecl) * 33 + eb] + zred[528 + (3 * 4 + ecl) * 33 + eb] + bc[col];
        float ig = sigmoidf_(zi);
        float fg = sigmoidf_(zf);
        float gg = sigmoidf_(zg);      // reference applies sigmoid to g
        float ct = tanhf_(zc);
        float* cp = cstate + (size_t)eb * 1024 + col;
        float cv = fg * (*cp) + ig * ct;
        *cp = cv;
        float hv = gg * tanhf_(cv);
        hbuf[(size_t)((t + 1) & 1) * 32768 + (size_t)eb * 1024 + col] = hv;
        states[((size_t)t * 32 + eb) * 1024 + col] = hv;
    }
}

// ---------------------------------------------------------------------------
// gemm1: out[b][t][:] = relu(states[t*32+b][:] @ Wo + bo)
// fp32 VALU, 128x128 tile, BK=16, 8x8 per thread, 16 KB LDS. grid 128*8.
// ---------------------------------------------------------------------------
__global__ __launch_bounds__(256) void k_gemm1(
    const float* __restrict__ A, const float* __restrict__ Wo,
    const float* __restrict__ bo, float* __restrict__ outp)
{
    __shared__ float Ash[16 * 128];   // [k][m]
    __shared__ float Bsh[16 * 128];   // [k][n]
    int tid = threadIdx.x;
    int bm = blockIdx.x >> 3, bn = blockIdx.x & 7;
    int r0 = bm * 128, n0 = bn * 128;
    int mg = tid >> 4, ng = tid & 15;
    int m0 = mg * 8, n0l = ng * 8;
    int sm = tid >> 1, skh = (tid & 1) * 8;     // A staging: row sm, k-off skh
    int sk = tid >> 4, snof = (tid & 15) * 8;   // B staging: k-row sk, n-off snof
    const float* aptr = A + (size_t)(r0 + sm) * 1024 + skh;

    float acc[8][8];
    for (int i = 0; i < 8; i++)
        for (int j = 0; j < 8; j++) acc[i][j] = 0.f;

    for (int k0 = 0; k0 < 1024; k0 += 16) {
        float4 av0 = *(const float4*)(aptr + k0);
        float4 av1 = *(const float4*)(aptr + k0 + 4);
        float4 bv0 = *(const float4*)(Wo + (size_t)(k0 + sk) * 1024 + n0 + snof);
        float4 bv1 = *(const float4*)(Wo + (size_t)(k0 + sk) * 1024 + n0 + snof + 4);
        Ash[(skh + 0) * 128 + sm] = av0.x;
        Ash[(skh + 1) * 128 + sm] = av0.y;
        Ash[(skh + 2) * 128 + sm] = av0.z;
        Ash[(skh + 3) * 128 + sm] = av0.w;
        Ash[(skh + 4) * 128 + sm] = av1.x;
        Ash[(skh + 5) * 128 + sm] = av1.y;
        Ash[(skh + 6) * 128 + sm] = av1.z;
        Ash[(skh + 7) * 128 + sm] = av1.w;
        *(float4*)&Bsh[sk * 128 + snof] = bv0;
        *(float4*)&Bsh[sk * 128 + snof + 4] = bv1;
        __syncthreads();
#pragma unroll
        for (int k = 0; k < 16; k++) {
            float4 a0 = *(const float4*)&Ash[k * 128 + m0];
            float4 a1 = *(const float4*)&Ash[k * 128 + m0 + 4];
            float4 b0 = *(const float4*)&Bsh[k * 128 + n0l];
            float4 b1 = *(const float4*)&Bsh[k * 128 + n0l + 4];
            float aa[8], bb[8];
            aa[0] = a0.x; aa[1] = a0.y; aa[2] = a0.z; aa[3] = a0.w;
            aa[4] = a1.x; aa[5] = a1.y; aa[6] = a1.z; aa[7] = a1.w;
            bb[0] = b0.x; bb[1] = b0.y; bb[2] = b0.z; bb[3] = b0.w;
            bb[4] = b1.x; bb[5] = b1.y; bb[6] = b1.z; bb[7] = b1.w;
#pragma unroll
            for (int i = 0; i < 8; i++)
#pragma unroll
                for (int j = 0; j < 8; j++)
                    acc[i][j] = __builtin_fmaf(aa[i], bb[j], acc[i][j]);
        }
        __syncthreads();
    }
    float fbs[8];
#pragma unroll
    for (int j = 0; j < 8; j++) fbs[j] = bo[n0 + n0l + j];
    for (int i = 0; i < 8; i++) {
        int R = r0 + m0 + i;     // R = t*32 + b
        size_t rowoff = (size_t)(R & 31) * 524288 + (size_t)(R >> 5) * 1024 + n0 + n0l;
#pragma unroll
        for (int j = 0; j < 8; j++) {
            float v = acc[i][j] + fbs[j];
            outp[rowoff + j] = v > 0.f ? v : 0.f;
        }
    }
}

extern "C" void kernel_launch(void* const* d_in, const int* in_sizes, int n_in,
                              void* d_out, int out_size, void* d_ws, size_t ws_size,
                              hipStream_t stream)
{
    const float* x   = (const float*)d_in[0];
    const float* Wi  = (const float*)d_in[1];
    const float* Ui  = (const float*)d_in[2];
    const float* Wf  = (const float*)d_in[3];
    const float* Uf  = (const float*)d_in[4];
    const float* Wg  = (const float*)d_in[5];
    const float* Ug  = (const float*)d_in[6];
    const float* Wc  = (const float*)d_in[7];
    const float* Uc  = (const float*)d_in[8];
    const float* Wo  = (const float*)d_in[9];
    const float* bi  = (const float*)d_in[10];
    const float* bfv = (const float*)d_in[11];
    const float* bg  = (const float*)d_in[12];
    const float* bc  = (const float*)d_in[13];
    const float* bo  = (const float*)d_in[14];

    float* ws     = (float*)d_ws;
    float* hbuf   = ws + OFF_H;
    float* cstate = ws + OFF_C;
    float* states = ws + OFF_STATES;
    float* outp   = (float*)d_out;

    k_init<<<256, 256, 0, stream>>>(hbuf, cstate);
    k_prefill<<<2048, 256, 0, stream>>>(outp);
    for (int t = 0; t < 512; t++) {
        k_step<<<256, 256, 0, stream>>>(x, Wi, Wf, Wg, Wc, Ui, Uf, Ug, Uc,
                                        bi, bfv, bg, bc, hbuf, cstate, states, t);
    }
    k_gemm1<<<1024, 256, 0, stream>>>(states, Wo, bo, outp);
}

// Round 9
// 34675.690 us; speedup vs baseline: 1.8934x; 1.8934x over previous
//
#include <hip/hip_runtime.h>

// ---- workspace layout (float-element offsets), total ~84.4 MB ----
// hbuf   : f32 [2][32][1024]   ping-pong hidden state (256 KB)
// cstate : f32 [32][1024]      cell state             (128 KB)
// xpc    : f32 [1024][4096]    x@W chunk (32 steps)   (16 MB)
// states : f32 [16384][1024]   all h_t, row = t*32+b  (64 MB)
#define OFF_H      0ull
#define OFF_C      65536ull
#define OFF_XPC    131072ull
#define OFF_STATES 4325376ull

static __device__ inline float sigmoidf_(float x) { return 1.f / (1.f + __expf(-x)); }
static __device__ inline float tanhf_(float x) { return 1.f - 2.f / (1.f + __expf(2.f * x)); }

// ---------------------------------------------------------------------------
// init: zero hbuf (65536 f32) and cstate (32768 f32). grid 256 x 256.
// ---------------------------------------------------------------------------
__global__ __launch_bounds__(256) void k_init(float* hb, float* cs) {
    int i = blockIdx.x * 256 + threadIdx.x;
    hb[i] = 0.f;
    if (i < 32768) cs[i] = 0.f;
}

// ---------------------------------------------------------------------------
// gemm0 (one 32-step chunk): xpc[Rl][4096] = x[b][t0+(Rl>>5)][:] @ [Wi|Wf|Wg|Wc] + b
// where Rl = local row 0..1023, b = Rl&31. fp32 VALU, 128x128 tile, BK=16,
// 8x8/thread, 16 KB LDS. grid = 8*32 = 256 blocks.
// ---------------------------------------------------------------------------
__global__ __launch_bounds__(256) void k_gemm0(
    const float* __restrict__ x,
    const float* __restrict__ Wi, const float* __restrict__ Wf,
    const float* __restrict__ Wg, const float* __restrict__ Wc,
    const float* __restrict__ bi, const float* __restrict__ bfv,
    const float* __restrict__ bg, const float* __restrict__ bc,
    float* __restrict__ xpc, int t0)
{
    __shared__ float Ash[16 * 128];   // [k][m]
    __shared__ float Bsh[16 * 128];   // [k][n]
    int tid = threadIdx.x;
    int bm = blockIdx.x >> 5, bn = blockIdx.x & 31;
    int r0 = bm * 128, n0 = bn * 128;
    int gate = bn >> 3;
    int nloc = (bn & 7) * 128;        // col offset inside the gate's 1024
    const float* W; const float* bias;
    if (gate == 0)      { W = Wi; bias = bi; }
    else if (gate == 1) { W = Wf; bias = bfv; }
    else if (gate == 2) { W = Wg; bias = bg; }
    else                { W = Wc; bias = bc; }

    int mg = tid >> 4, ng = tid & 15;
    int m0 = mg * 8, n0l = ng * 8;
    int sm = tid >> 1, skh = (tid & 1) * 8;     // A staging: row sm, k-off skh
    int sk = tid >> 4, snof = (tid & 15) * 8;   // B staging: k-row sk, n-off snof
    int Ra = r0 + sm;
    const float* aptr = x + (size_t)(Ra & 31) * 524288
                          + (size_t)(t0 + (Ra >> 5)) * 1024 + skh;

    float acc[8][8];
    for (int i = 0; i < 8; i++)
        for (int j = 0; j < 8; j++) acc[i][j] = 0.f;

    for (int k0 = 0; k0 < 1024; k0 += 16) {
        float4 av0 = *(const float4*)(aptr + k0);
        float4 av1 = *(const float4*)(aptr + k0 + 4);
        float4 bv0 = *(const float4*)(W + (size_t)(k0 + sk) * 1024 + nloc + snof);
        float4 bv1 = *(const float4*)(W + (size_t)(k0 + sk) * 1024 + nloc + snof + 4);
        Ash[(skh + 0) * 128 + sm] = av0.x;
        Ash[(skh + 1) * 128 + sm] = av0.y;
        Ash[(skh + 2) * 128 + sm] = av0.z;
        Ash[(skh + 3) * 128 + sm] = av0.w;
        Ash[(skh + 4) * 128 + sm] = av1.x;
        Ash[(skh + 5) * 128 + sm] = av1.y;
        Ash[(skh + 6) * 128 + sm] = av1.z;
        Ash[(skh + 7) * 128 + sm] = av1.w;
        *(float4*)&Bsh[sk * 128 + snof] = bv0;
        *(float4*)&Bsh[sk * 128 + snof + 4] = bv1;
        __syncthreads();
#pragma unroll
        for (int k = 0; k < 16; k++) {
            float4 a0 = *(const float4*)&Ash[k * 128 + m0];
            float4 a1 = *(const float4*)&Ash[k * 128 + m0 + 4];
            float4 b0 = *(const float4*)&Bsh[k * 128 + n0l];
            float4 b1 = *(const float4*)&Bsh[k * 128 + n0l + 4];
            float aa[8], bb[8];
            aa[0] = a0.x; aa[1] = a0.y; aa[2] = a0.z; aa[3] = a0.w;
            aa[4] = a1.x; aa[5] = a1.y; aa[6] = a1.z; aa[7] = a1.w;
            bb[0] = b0.x; bb[1] = b0.y; bb[2] = b0.z; bb[3] = b0.w;
            bb[4] = b1.x; bb[5] = b1.y; bb[6] = b1.z; bb[7] = b1.w;
#pragma unroll
            for (int i = 0; i < 8; i++)
#pragma unroll
                for (int j = 0; j < 8; j++)
                    acc[i][j] = __builtin_fmaf(aa[i], bb[j], acc[i][j]);
        }
        __syncthreads();
    }
    float fbs[8];
#pragma unroll
    for (int j = 0; j < 8; j++) fbs[j] = bias[nloc + n0l + j];
    for (int i = 0; i < 8; i++) {
        size_t rowoff = (size_t)(r0 + m0 + i) * 4096 + n0 + n0l;
#pragma unroll
        for (int j = 0; j < 8; j++)
            xpc[rowoff + j] = acc[i][j] + fbs[j];
    }
}

// ---------------------------------------------------------------------------
// one recurrent step: z = xpc_t + h_t @ [Ui|Uf|Ug|Uc]; gates; c,h update.
// 256 blocks x 256 thr; block owns 4 h-cols (col0 = bid*4).
// Thread (ks,b,g): K-half ks of h@U_g for the block's 4 columns.
// xpc row for step t = (t&31)*32 + b (chunk-local).
// ---------------------------------------------------------------------------
__global__ __launch_bounds__(256) void k_step(
    const float* __restrict__ Ui, const float* __restrict__ Uf,
    const float* __restrict__ Ug, const float* __restrict__ Uc,
    const float* __restrict__ xpc,
    float* hbuf, float* cstate, float* states, int t)
{
    __shared__ float zred[2 * 16 * 33];   // [ks][zc(16)][b(32)+pad]
    int tid = threadIdx.x;
    int bid = blockIdx.x;                 // 0..255
    int col0 = bid * 4;
    int ks = tid >> 7;                    // 0..1
    int b  = (tid >> 2) & 31;             // 0..31
    int g  = tid & 3;                     // 0..3

    const float* Bu;
    if (g == 0)      Bu = Ui;
    else if (g == 1) Bu = Uf;
    else if (g == 2) Bu = Ug;
    else             Bu = Uc;

    const float* arow  = hbuf + (size_t)(t & 1) * 32768 + (size_t)b * 1024 + ks * 512;
    const float* bbase = Bu + col0 + (size_t)ks * 512 * 1024;

    float acc0 = 0.f, acc1 = 0.f, acc2 = 0.f, acc3 = 0.f;
    for (int kb = 0; kb < 64; kb++) {
        float4 a0 = *(const float4*)(arow + kb * 8);
        float4 a1 = *(const float4*)(arow + kb * 8 + 4);
        float aa[8];
        aa[0] = a0.x; aa[1] = a0.y; aa[2] = a0.z; aa[3] = a0.w;
        aa[4] = a1.x; aa[5] = a1.y; aa[6] = a1.z; aa[7] = a1.w;
#pragma unroll
        for (int j = 0; j < 8; j++) {
            float4 bv = *(const float4*)(bbase + (size_t)(kb * 8 + j) * 1024);
            acc0 = __builtin_fmaf(aa[j], bv.x, acc0);
            acc1 = __builtin_fmaf(aa[j], bv.y, acc1);
            acc2 = __builtin_fmaf(aa[j], bv.z, acc2);
            acc3 = __builtin_fmaf(aa[j], bv.w, acc3);
        }
    }
    zred[ks * 528 + (g * 4 + 0) * 33 + b] = acc0;
    zred[ks * 528 + (g * 4 + 1) * 33 + b] = acc1;
    zred[ks * 528 + (g * 4 + 2) * 33 + b] = acc2;
    zred[ks * 528 + (g * 4 + 3) * 33 + b] = acc3;
    __syncthreads();

    if (tid < 128) {
        int eb = tid >> 2, ecl = tid & 3;
        int col = col0 + ecl;
        const float* xr = xpc + ((size_t)(t & 31) * 32 + eb) * 4096 + col;
        float zi = zred[(0 * 4 + ecl) * 33 + eb] + zred[528 + (0 * 4 + ecl) * 33 + eb] + xr[0];
        float zf = zred[(1 * 4 + ecl) * 33 + eb] + zred[528 + (1 * 4 + ecl) * 33 + eb] + xr[1024];
        float zg = zred[(2 * 4 + ecl) * 33 + eb] + zred[528 + (2 * 4 + ecl) * 33 + eb] + xr[2048];
        float zc = zred[(3 * 4 + ecl) * 33 + eb] + zred[528 + (3 * 4 + ecl) * 33 + eb] + xr[3072];
        float ig = sigmoidf_(zi);
        float fg = sigmoidf_(zf);
        float gg = sigmoidf_(zg);      // reference applies sigmoid to g
        float ct = tanhf_(zc);
        float* cp = cstate + (size_t)eb * 1024 + col;
        float cv = fg * (*cp) + ig * ct;
        *cp = cv;
        float hv = gg * tanhf_(cv);
        hbuf[(size_t)((t + 1) & 1) * 32768 + (size_t)eb * 1024 + col] = hv;
        states[((size_t)t * 32 + eb) * 1024 + col] = hv;
    }
}

// ---------------------------------------------------------------------------
// gemm1: out[b][t][:] = relu(states[t*32+b][:] @ Wo + bo)
// fp32 VALU, 128x128 tile, BK=16, 8x8/thread. grid 128*8 = 1024.
// ---------------------------------------------------------------------------
__global__ __launch_bounds__(256) void k_gemm1(
    const float* __restrict__ A, const float* __restrict__ Wo,
    const float* __restrict__ bo, float* __restrict__ outp)
{
    __shared__ float Ash[16 * 128];
    __shared__ float Bsh[16 * 128];
    int tid = threadIdx.x;
    int bm = blockIdx.x >> 3, bn = blockIdx.x & 7;
    int r0 = bm * 128, n0 = bn * 128;
    int mg = tid >> 4, ng = tid & 15;
    int m0 = mg * 8, n0l = ng * 8;
    int sm = tid >> 1, skh = (tid & 1) * 8;
    int sk = tid >> 4, snof = (tid & 15) * 8;
    const float* aptr = A + (size_t)(r0 + sm) * 1024 + skh;

    float acc[8][8];
    for (int i = 0; i < 8; i++)
        for (int j = 0; j < 8; j++) acc[i][j] = 0.f;

    for (int k0 = 0; k0 < 1024; k0 += 16) {
        float4 av0 = *(const float4*)(aptr + k0);
        float4 av1 = *(const float4*)(aptr + k0 + 4);
        float4 bv0 = *(const float4*)(Wo + (size_t)(k0 + sk) * 1024 + n0 + snof);
        float4 bv1 = *(const float4*)(Wo + (size_t)(k0 + sk) * 1024 + n0 + snof + 4);
        Ash[(skh + 0) * 128 + sm] = av0.x;
        Ash[(skh + 1) * 128 + sm] = av0.y;
        Ash[(skh + 2) * 128 + sm] = av0.z;
        Ash[(skh + 3) * 128 + sm] = av0.w;
        Ash[(skh + 4) * 128 + sm] = av1.x;
        Ash[(skh + 5) * 128 + sm] = av1.y;
        Ash[(skh + 6) * 128 + sm] = av1.z;
        Ash[(skh + 7) * 128 + sm] = av1.w;
        *(float4*)&Bsh[sk * 128 + snof] = bv0;
        *(float4*)&Bsh[sk * 128 + snof + 4] = bv1;
        __syncthreads();
#pragma unroll
        for (int k = 0; k < 16; k++) {
            float4 a0 = *(const float4*)&Ash[k * 128 + m0];
            float4 a1 = *(const float4*)&Ash[k * 128 + m0 + 4];
            float4 b0 = *(const float4*)&Bsh[k * 128 + n0l];
            float4 b1 = *(const float4*)&Bsh[k * 128 + n0l + 4];
            float aa[8], bb[8];
            aa[0] = a0.x; aa[1] = a0.y; aa[2] = a0.z; aa[3] = a0.w;
            aa[4] = a1.x; aa[5] = a1.y; aa[6] = a1.z; aa[7] = a1.w;
            bb[0] = b0.x; bb[1] = b0.y; bb[2] = b0.z; bb[3] = b0.w;
            bb[4] = b1.x; bb[5] = b1.y; bb[6] = b1.z; bb[7] = b1.w;
#pragma unroll
            for (int i = 0; i < 8; i++)
#pragma unroll
                for (int j = 0; j < 8; j++)
                    acc[i][j] = __builtin_fmaf(aa[i], bb[j], acc[i][j]);
        }
        __syncthreads();
    }
    float fbs[8];
#pragma unroll
    for (int j = 0; j < 8; j++) fbs[j] = bo[n0 + n0l + j];
    for (int i = 0; i < 8; i++) {
        int R = r0 + m0 + i;     // R = t*32 + b
        size_t rowoff = (size_t)(R & 31) * 524288 + (size_t)(R >> 5) * 1024 + n0 + n0l;
#pragma unroll
        for (int j = 0; j < 8; j++) {
            float v = acc[i][j] + fbs[j];
            outp[rowoff + j] = v > 0.f ? v : 0.f;
        }
    }
}

extern "C" void kernel_launch(void* const* d_in, const int* in_sizes, int n_in,
                              void* d_out, int out_size, void* d_ws, size_t ws_size,
                              hipStream_t stream)
{
    const float* x   = (const float*)d_in[0];
    const float* Wi  = (const float*)d_in[1];
    const float* Ui  = (const float*)d_in[2];
    const float* Wf  = (const float*)d_in[3];
    const float* Uf  = (const float*)d_in[4];
    const float* Wg  = (const float*)d_in[5];
    const float* Ug  = (const float*)d_in[6];
    const float* Wc  = (const float*)d_in[7];
    const float* Uc  = (const float*)d_in[8];
    const float* Wo  = (const float*)d_in[9];
    const float* bi  = (const float*)d_in[10];
    const float* bfv = (const float*)d_in[11];
    const float* bg  = (const float*)d_in[12];
    const float* bc  = (const float*)d_in[13];
    const float* bo  = (const float*)d_in[14];

    float* ws     = (float*)d_ws;
    float* hbuf   = ws + OFF_H;
    float* cstate = ws + OFF_C;
    float* xpc    = ws + OFF_XPC;
    float* states = ws + OFF_STATES;
    float* outp   = (float*)d_out;

    k_init<<<256, 256, 0, stream>>>(hbuf, cstate);
    for (int c = 0; c < 16; c++) {
        k_gemm0<<<256, 256, 0, stream>>>(x, Wi, Wf, Wg, Wc, bi, bfv, bg, bc,
                                         xpc, c * 32);
        for (int tt = 0; tt < 32; tt++) {
            int t = c * 32 + tt;
            k_step<<<256, 256, 0, stream>>>(Ui, Uf, Ug, Uc, xpc,
                                            hbuf, cstate, states, t);
        }
    }
    k_gemm1<<<1024, 256, 0, stream>>>(states, Wo, bo, outp);
}

// Round 10
// 24438.565 us; speedup vs baseline: 2.6865x; 1.4189x over previous
//
#include <hip/hip_runtime.h>

// ---- workspace layout (float-element offsets), total ~84.4 MB ----
// hbuf   : f32 [2][32][1024]   ping-pong hidden state (256 KB)
// cstate : f32 [32][1024]      cell state             (128 KB)
// bar    : int[64]             barrier: [0]=arrivals, [16]=released step
// xpc    : f32 [1024][4096]    x@W chunk (32 steps)   (16 MB)
// states : f32 [16384][1024]   all h_t, row = t*32+b  (64 MB)
#define OFF_H      0ull
#define OFF_C      65536ull
#define OFF_BAR    98304ull
#define OFF_XPC    131072ull
#define OFF_STATES 4325376ull

static __device__ inline float sigmoidf_(float x) { return 1.f / (1.f + __expf(-x)); }
static __device__ inline float tanhf_(float x) { return 1.f - 2.f / (1.f + __expf(2.f * x)); }

// ---------------------------------------------------------------------------
// init: zero hbuf (65536 f32), cstate (32768 f32), bar (64 ints).
// ---------------------------------------------------------------------------
__global__ __launch_bounds__(256) void k_init(float* hb, float* cs, int* bar) {
    int i = blockIdx.x * 256 + threadIdx.x;
    hb[i] = 0.f;
    if (i < 32768) cs[i] = 0.f;
    if (i < 64) bar[i] = 0;
}

// ---------------------------------------------------------------------------
// gemm0 (one 32-step chunk): xpc[Rl][4096] = x[b][t0+(Rl>>5)][:] @ [Wi|Wf|Wg|Wc] + b
// (unchanged from green round 9)
// ---------------------------------------------------------------------------
__global__ __launch_bounds__(256) void k_gemm0(
    const float* __restrict__ x,
    const float* __restrict__ Wi, const float* __restrict__ Wf,
    const float* __restrict__ Wg, const float* __restrict__ Wc,
    const float* __restrict__ bi, const float* __restrict__ bfv,
    const float* __restrict__ bg, const float* __restrict__ bc,
    float* __restrict__ xpc, int t0)
{
    __shared__ float Ash[16 * 128];
    __shared__ float Bsh[16 * 128];
    int tid = threadIdx.x;
    int bm = blockIdx.x >> 5, bn = blockIdx.x & 31;
    int r0 = bm * 128, n0 = bn * 128;
    int gate = bn >> 3;
    int nloc = (bn & 7) * 128;
    const float* W; const float* bias;
    if (gate == 0)      { W = Wi; bias = bi; }
    else if (gate == 1) { W = Wf; bias = bfv; }
    else if (gate == 2) { W = Wg; bias = bg; }
    else                { W = Wc; bias = bc; }

    int mg = tid >> 4, ng = tid & 15;
    int m0 = mg * 8, n0l = ng * 8;
    int sm = tid >> 1, skh = (tid & 1) * 8;
    int sk = tid >> 4, snof = (tid & 15) * 8;
    int Ra = r0 + sm;
    const float* aptr = x + (size_t)(Ra & 31) * 524288
                          + (size_t)(t0 + (Ra >> 5)) * 1024 + skh;

    float acc[8][8];
    for (int i = 0; i < 8; i++)
        for (int j = 0; j < 8; j++) acc[i][j] = 0.f;

    for (int k0 = 0; k0 < 1024; k0 += 16) {
        float4 av0 = *(const float4*)(aptr + k0);
        float4 av1 = *(const float4*)(aptr + k0 + 4);
        float4 bv0 = *(const float4*)(W + (size_t)(k0 + sk) * 1024 + nloc + snof);
        float4 bv1 = *(const float4*)(W + (size_t)(k0 + sk) * 1024 + nloc + snof + 4);
        Ash[(skh + 0) * 128 + sm] = av0.x;
        Ash[(skh + 1) * 128 + sm] = av0.y;
        Ash[(skh + 2) * 128 + sm] = av0.z;
        Ash[(skh + 3) * 128 + sm] = av0.w;
        Ash[(skh + 4) * 128 + sm] = av1.x;
        Ash[(skh + 5) * 128 + sm] = av1.y;
        Ash[(skh + 6) * 128 + sm] = av1.z;
        Ash[(skh + 7) * 128 + sm] = av1.w;
        *(float4*)&Bsh[sk * 128 + snof] = bv0;
        *(float4*)&Bsh[sk * 128 + snof + 4] = bv1;
        __syncthreads();
#pragma unroll
        for (int k = 0; k < 16; k++) {
            float4 a0 = *(const float4*)&Ash[k * 128 + m0];
            float4 a1 = *(const float4*)&Ash[k * 128 + m0 + 4];
            float4 b0 = *(const float4*)&Bsh[k * 128 + n0l];
            float4 b1 = *(const float4*)&Bsh[k * 128 + n0l + 4];
            float aa[8], bb[8];
            aa[0] = a0.x; aa[1] = a0.y; aa[2] = a0.z; aa[3] = a0.w;
            aa[4] = a1.x; aa[5] = a1.y; aa[6] = a1.z; aa[7] = a1.w;
            bb[0] = b0.x; bb[1] = b0.y; bb[2] = b0.z; bb[3] = b0.w;
            bb[4] = b1.x; bb[5] = b1.y; bb[6] = b1.z; bb[7] = b1.w;
#pragma unroll
            for (int i = 0; i < 8; i++)
#pragma unroll
                for (int j = 0; j < 8; j++)
                    acc[i][j] = __builtin_fmaf(aa[i], bb[j], acc[i][j]);
        }
        __syncthreads();
    }
    float fbs[8];
#pragma unroll
    for (int j = 0; j < 8; j++) fbs[j] = bias[nloc + n0l + j];
    for (int i = 0; i < 8; i++) {
        size_t rowoff = (size_t)(r0 + m0 + i) * 4096 + n0 + n0l;
#pragma unroll
        for (int j = 0; j < 8; j++)
            xpc[rowoff + j] = acc[i][j] + fbs[j];
    }
}

// ---------------------------------------------------------------------------
// k_scan32: 32 LSTM steps in ONE persistent launch. 256 blocks x 256 thr,
// 1 block/CU (all co-resident). Block owns 4 h-cols (col0=bid*4) x 4 gates
// = 16 z-cols. Thread (ku=tid>>2, cg=tid&3) holds U_cg[k=ku*16..+16][4 cols]
// in 16 float4 REGISTERS — zero U traffic in the step loop.
// Per step: 8 passes over 4 batches: stage h(t) slice to LDS, 256 FMA/thread,
// k-reduce 64 partials in LDS, 16 owner threads do gate math (c-state in LDS,
// persists across the 32 steps; saved to global at launch end).
// Grid barrier between steps: monotone arrive-counter + release-step flag
// (gen = global t, continuous across the 16 chunk launches).
// ---------------------------------------------------------------------------
__global__ __launch_bounds__(256, 1) void k_scan32(
    const float* __restrict__ Ui, const float* __restrict__ Uf,
    const float* __restrict__ Ug, const float* __restrict__ Uc,
    const float* __restrict__ xpc,
    float* hbuf, float* cstate, float* states, int* bar, int t0)
{
    __shared__ float hsh[4 * 1024];    // 16 KB  [bb(4)][k(1024)]
    __shared__ float zbuf[64 * 68];    // 17.4 KB [ku][bgc(64) pad->68]
    __shared__ float zfin[64];         // [bb*16 + g*4 + c]
    __shared__ float csh[16 * 8];      // c-state: [owner(16)][pass(8)]
    int tid = threadIdx.x;
    int col0 = blockIdx.x * 4;
    int ku = tid >> 2, cg = tid & 3;
    const float* Bu;
    if (cg == 0) Bu = Ui; else if (cg == 1) Bu = Uf;
    else if (cg == 2) Bu = Ug; else Bu = Uc;

    // persistent U slice in registers: ur[kk] = U[ku*16+kk][col0..col0+3]
    float4 ur[16];
#pragma unroll
    for (int kk = 0; kk < 16; kk++)
        ur[kk] = *(const float4*)(Bu + (size_t)(ku * 16 + kk) * 1024 + col0);

    int ob = tid >> 2, oc = tid & 3;   // owner roles (tid < 16)
    if (tid < 16) {
        for (int p = 0; p < 8; p++)
            csh[tid * 8 + p] = cstate[(size_t)(p * 4 + ob) * 1024 + col0 + oc];
    }
    __syncthreads();

    for (int tt = 0; tt < 32; tt++) {
        int t = t0 + tt;
        const float* hb = hbuf + (size_t)(t & 1) * 32768;
        float* hn = hbuf + (size_t)((t + 1) & 1) * 32768;

        for (int p = 0; p < 8; p++) {
            // owners: fetch xp for this pass early (hidden behind stage+compute)
            float xg0 = 0.f, xg1 = 0.f, xg2 = 0.f, xg3 = 0.f;
            if (tid < 16) {
                const float* xr = xpc + (size_t)(tt * 32 + p * 4 + ob) * 4096 + col0 + oc;
                xg0 = xr[0];
                xg1 = xr[1024];
                xg2 = xr[2048];
                xg3 = xr[3072];
            }
            // stage h(t) for batches p*4..p*4+3: 4096 f32, 4 float4/thread
#pragma unroll
            for (int q = 0; q < 4; q++) {
                int f = tid + q * 256;
                int r = f >> 8, k4 = f & 255;
                *(float4*)&hsh[r * 1024 + k4 * 4] =
                    *(const float4*)(hb + (size_t)(p * 4 + r) * 1024 + k4 * 4);
            }
            __syncthreads();

            float acc[4][4];
            for (int b = 0; b < 4; b++)
                for (int c = 0; c < 4; c++) acc[b][c] = 0.f;
#pragma unroll
            for (int b = 0; b < 4; b++) {
#pragma unroll
                for (int k4 = 0; k4 < 4; k4++) {
                    float4 hv = *(const float4*)&hsh[b * 1024 + ku * 16 + k4 * 4];
                    float4 u0 = ur[k4 * 4 + 0];
                    float4 u1 = ur[k4 * 4 + 1];
                    float4 u2 = ur[k4 * 4 + 2];
                    float4 u3 = ur[k4 * 4 + 3];
                    acc[b][0] = __builtin_fmaf(hv.x, u0.x, acc[b][0]);
                    acc[b][1] = __builtin_fmaf(hv.x, u0.y, acc[b][1]);
                    acc[b][2] = __builtin_fmaf(hv.x, u0.z, acc[b][2]);
                    acc[b][3] = __builtin_fmaf(hv.x, u0.w, acc[b][3]);
                    acc[b][0] = __builtin_fmaf(hv.y, u1.x, acc[b][0]);
                    acc[b][1] = __builtin_fmaf(hv.y, u1.y, acc[b][1]);
                    acc[b][2] = __builtin_fmaf(hv.y, u1.z, acc[b][2]);
                    acc[b][3] = __builtin_fmaf(hv.y, u1.w, acc[b][3]);
                    acc[b][0] = __builtin_fmaf(hv.z, u2.x, acc[b][0]);
                    acc[b][1] = __builtin_fmaf(hv.z, u2.y, acc[b][1]);
                    acc[b][2] = __builtin_fmaf(hv.z, u2.z, acc[b][2]);
                    acc[b][3] = __builtin_fmaf(hv.z, u2.w, acc[b][3]);
                    acc[b][0] = __builtin_fmaf(hv.w, u3.x, acc[b][0]);
                    acc[b][1] = __builtin_fmaf(hv.w, u3.y, acc[b][1]);
                    acc[b][2] = __builtin_fmaf(hv.w, u3.z, acc[b][2]);
                    acc[b][3] = __builtin_fmaf(hv.w, u3.w, acc[b][3]);
                }
            }
            // dump partials: zbuf[ku][b*16 + cg*4 + c]
#pragma unroll
            for (int b = 0; b < 4; b++) {
                float4 v;
                v.x = acc[b][0]; v.y = acc[b][1]; v.z = acc[b][2]; v.w = acc[b][3];
                *(float4*)&zbuf[ku * 68 + b * 16 + cg * 4] = v;
            }
            __syncthreads();

            // k-reduction: 64 threads, one (b,g,c) each
            if (tid < 64) {
                float s = 0.f;
                for (int u = 0; u < 64; u++) s += zbuf[u * 68 + tid];
                zfin[tid] = s;
            }
            __syncthreads();

            // gate math: 16 owners, one (b=p*4+ob, col=col0+oc) each
            if (tid < 16) {
                int b = p * 4 + ob;
                float zi = zfin[ob * 16 + 0 * 4 + oc] + xg0;
                float zf = zfin[ob * 16 + 1 * 4 + oc] + xg1;
                float zg = zfin[ob * 16 + 2 * 4 + oc] + xg2;
                float zc = zfin[ob * 16 + 3 * 4 + oc] + xg3;
                float ig = sigmoidf_(zi);
                float fg = sigmoidf_(zf);
                float gg = sigmoidf_(zg);   // reference applies sigmoid to g
                float ct = tanhf_(zc);
                float cv = fg * csh[tid * 8 + p] + ig * ct;
                csh[tid * 8 + p] = cv;
                float hv = gg * tanhf_(cv);
                hn[(size_t)b * 1024 + col0 + oc] = hv;
                states[((size_t)t * 32 + b) * 1024 + col0 + oc] = hv;
            }
            __syncthreads();   // hsh/zbuf/zfin reuse next pass
        }

        // grid barrier: publish h(t+1), wait for all 256 blocks
        if (tid == 0) {
            __threadfence();                       // release h writes device-wide
            int a = atomicAdd(&bar[0], 1) + 1;     // arrivals accumulate monotonically
            if (a == 256 * (t + 1)) atomicExch(&bar[16], t + 1);
        }
        if (tid == 0) {
            while (atomicAdd(&bar[16], 0) <= t) { }
        }
        __syncthreads();
        __threadfence();                           // acquire remote h before next read
    }

    // persist c-state for the next chunk launch
    if (tid < 16) {
        for (int p = 0; p < 8; p++)
            cstate[(size_t)(p * 4 + ob) * 1024 + col0 + oc] = csh[tid * 8 + p];
    }
}

// ---------------------------------------------------------------------------
// gemm1: out[b][t][:] = relu(states[t*32+b][:] @ Wo + bo)  (unchanged, green)
// ---------------------------------------------------------------------------
__global__ __launch_bounds__(256) void k_gemm1(
    const float* __restrict__ A, const float* __restrict__ Wo,
    const float* __restrict__ bo, float* __restrict__ outp)
{
    __shared__ float Ash[16 * 128];
    __shared__ float Bsh[16 * 128];
    int tid = threadIdx.x;
    int bm = blockIdx.x >> 3, bn = blockIdx.x & 7;
    int r0 = bm * 128, n0 = bn * 128;
    int mg = tid >> 4, ng = tid & 15;
    int m0 = mg * 8, n0l = ng * 8;
    int sm = tid >> 1, skh = (tid & 1) * 8;
    int sk = tid >> 4, snof = (tid & 15) * 8;
    const float* aptr = A + (size_t)(r0 + sm) * 1024 + skh;

    float acc[8][8];
    for (int i = 0; i < 8; i++)
        for (int j = 0; j < 8; j++) acc[i][j] = 0.f;

    for (int k0 = 0; k0 < 1024; k0 += 16) {
        float4 av0 = *(const float4*)(aptr + k0);
        float4 av1 = *(const float4*)(aptr + k0 + 4);
        float4 bv0 = *(const float4*)(Wo + (size_t)(k0 + sk) * 1024 + n0 + snof);
        float4 bv1 = *(const float4*)(Wo + (size_t)(k0 + sk) * 1024 + n0 + snof + 4);
        Ash[(skh + 0) * 128 + sm] = av0.x;
        Ash[(skh + 1) * 128 + sm] = av0.y;
        Ash[(skh + 2) * 128 + sm] = av0.z;
        Ash[(skh + 3) * 128 + sm] = av0.w;
        Ash[(skh + 4) * 128 + sm] = av1.x;
        Ash[(skh + 5) * 128 + sm] = av1.y;
        Ash[(skh + 6) * 128 + sm] = av1.z;
        Ash[(skh + 7) * 128 + sm] = av1.w;
        *(float4*)&Bsh[sk * 128 + snof] = bv0;
        *(float4*)&Bsh[sk * 128 + snof + 4] = bv1;
        __syncthreads();
#pragma unroll
        for (int k = 0; k < 16; k++) {
            float4 a0 = *(const float4*)&Ash[k * 128 + m0];
            float4 a1 = *(const float4*)&Ash[k * 128 + m0 + 4];
            float4 b0 = *(const float4*)&Bsh[k * 128 + n0l];
            float4 b1 = *(const float4*)&Bsh[k * 128 + n0l + 4];
            float aa[8], bb[8];
            aa[0] = a0.x; aa[1] = a0.y; aa[2] = a0.z; aa[3] = a0.w;
            aa[4] = a1.x; aa[5] = a1.y; aa[6] = a1.z; aa[7] = a1.w;
            bb[0] = b0.x; bb[1] = b0.y; bb[2] = b0.z; bb[3] = b0.w;
            bb[4] = b1.x; bb[5] = b1.y; bb[6] = b1.z; bb[7] = b1.w;
#pragma unroll
            for (int i = 0; i < 8; i++)
#pragma unroll
                for (int j = 0; j < 8; j++)
                    acc[i][j] = __builtin_fmaf(aa[i], bb[j], acc[i][j]);
        }
        __syncthreads();
    }
    float fbs[8];
#pragma unroll
    for (int j = 0; j < 8; j++) fbs[j] = bo[n0 + n0l + j];
    for (int i = 0; i < 8; i++) {
        int R = r0 + m0 + i;
        size_t rowoff = (size_t)(R & 31) * 524288 + (size_t)(R >> 5) * 1024 + n0 + n0l;
#pragma unroll
        for (int j = 0; j < 8; j++) {
            float v = acc[i][j] + fbs[j];
            outp[rowoff + j] = v > 0.f ? v : 0.f;
        }
    }
}

extern "C" void kernel_launch(void* const* d_in, const int* in_sizes, int n_in,
                              void* d_out, int out_size, void* d_ws, size_t ws_size,
                              hipStream_t stream)
{
    const float* x   = (const float*)d_in[0];
    const float* Wi  = (const float*)d_in[1];
    const float* Ui  = (const float*)d_in[2];
    const float* Wf  = (const float*)d_in[3];
    const float* Uf  = (const float*)d_in[4];
    const float* Wg  = (const float*)d_in[5];
    const float* Ug  = (const float*)d_in[6];
    const float* Wc  = (const float*)d_in[7];
    const float* Uc  = (const float*)d_in[8];
    const float* Wo  = (const float*)d_in[9];
    const float* bi  = (const float*)d_in[10];
    const float* bfv = (const float*)d_in[11];
    const float* bg  = (const float*)d_in[12];
    const float* bc  = (const float*)d_in[13];
    const float* bo  = (const float*)d_in[14];

    float* ws     = (float*)d_ws;
    float* hbuf   = ws + OFF_H;
    float* cstate = ws + OFF_C;
    int*   bar    = (int*)(ws + OFF_BAR);
    float* xpc    = ws + OFF_XPC;
    float* states = ws + OFF_STATES;
    float* outp   = (float*)d_out;

    k_init<<<256, 256, 0, stream>>>(hbuf, cstate, bar);
    for (int c = 0; c < 16; c++) {
        k_gemm0<<<256, 256, 0, stream>>>(x, Wi, Wf, Wg, Wc, bi, bfv, bg, bc,
                                         xpc, c * 32);
        k_scan32<<<256, 256, 0, stream>>>(Ui, Uf, Ug, Uc, xpc,
                                          hbuf, cstate, states, bar, c * 32);
    }
    k_gemm1<<<1024, 256, 0, stream>>>(states, Wo, bo, outp);
}